// Round 7
// baseline (232.581 us; speedup 1.0000x reference)
//
#include <hip/hip_runtime.h>
#include <hip/hip_cooperative_groups.h>
#include <stdint.h>

namespace cg = cooperative_groups;

#define NB 4096          // number of boxes
#define NBLK 64          // 64 blocks of 64 boxes
#define IOU_THR 0.5f
#define ECAP 1024        // entry capacity per source block bucket
#define NTRI (NBLK * (NBLK + 1) / 2)   // 2080 upper-triangle tiles
#define GRID 256         // cooperative grid: 1 block per CU

typedef unsigned long long u64;

__device__ __forceinline__ u64 readlane64(u64 v, int lane) {
    unsigned lo = (unsigned)__builtin_amdgcn_readlane((int)(unsigned)(v & 0xffffffffull), lane);
    unsigned hi = (unsigned)__builtin_amdgcn_readlane((int)(unsigned)(v >> 32), lane);
    return ((u64)hi << 32) | (u64)lo;
}

__global__ void __launch_bounds__(256, 1) fcos_fused(
        const float* __restrict__ boxes, const float* __restrict__ scores,
        const int* __restrict__ cls, const float* __restrict__ loc,
        const float* __restrict__ deltas, const int* __restrict__ stride_p,
        float* __restrict__ keep_out, float* __restrict__ pred_out,
        float* __restrict__ maxc, int* __restrict__ sidx,
        int* __restrict__ counts, uint4* __restrict__ entries) {
    cg::grid_group grid = cg::this_grid();
    __shared__ __align__(16) float sh[NB];     // 16 KB (rank scores)
    __shared__ float red[4];
    __shared__ float4 cbs[4][64];              // per-wave column-box quarters
    __shared__ float  cas[4][64];

    const int blk  = blockIdx.x;
    const int t    = threadIdx.x;
    const int wave = t >> 6, lane = t & 63;

    // ================= Phase A =================
    // every block: rank 16 boxes (wave-per-box, 4 boxes/wave)
    {
        for (int i = t; i < NB; i += 256) sh[i] = scores[i];
        __syncthreads();
        int base = blk * 16 + wave * 4;
        float my0 = sh[base + 0], my1 = sh[base + 1];
        float my2 = sh[base + 2], my3 = sh[base + 3];
        int c0 = 0, c1 = 0, c2 = 0, c3 = 0;
#pragma unroll 8
        for (int k = 0; k < 64; ++k) {
            int j = lane + k * 64;             // 2-way LDS bank alias: free
            float sj = sh[j];
            c0 += (sj > my0) || (sj == my0 && j < base + 0);
            c1 += (sj > my1) || (sj == my1 && j < base + 1);
            c2 += (sj > my2) || (sj == my2 && j < base + 2);
            c3 += (sj > my3) || (sj == my3 && j < base + 3);
        }
        for (int o = 32; o > 0; o >>= 1) {
            c0 += __shfl_down(c0, o); c1 += __shfl_down(c1, o);
            c2 += __shfl_down(c2, o); c3 += __shfl_down(c3, o);
        }
        if (lane == 0) {
            sidx[c0] = base + 0; sidx[c1] = base + 1;
            sidx[c2] = base + 2; sidx[c3] = base + 3;
        }
    }
    // blocks 0-63: pred boxes + centerness; block 64: maxc + zero counters
    if (blk < 64) {
        int i = blk * 256 + t;
        float s = (float)stride_p[0];
        float2 p = ((const float2*)loc)[i];
        float4 d = ((const float4*)deltas)[i];
        float c0 = fmaxf(d.x, 0.f), c1 = fmaxf(d.y, 0.f);
        float c2 = fmaxf(d.z, 0.f), c3 = fmaxf(d.w, 0.f);
        float b0 = p.x - c0 * s;
        float b1 = p.y - c1 * s;
        float b2 = p.x + c2 * s;
        float b3 = p.y + c3 * s;
        float lr_min = fminf(d.x, d.z), tb_min = fminf(d.y, d.w);
        float lr_max = fmaxf(d.x, d.z), tb_max = fmaxf(d.y, d.w);
        float cent = sqrtf((lr_min * tb_min) / (lr_max * tb_max));
        if (d.x == -1.f && d.y == -1.f && d.z == -1.f && d.w == -1.f) cent = -1.f;
        float* o = pred_out + (size_t)i * 5;
        o[0] = b0; o[1] = b1; o[2] = b2; o[3] = b3; o[4] = cent;
    } else if (blk == 64) {
        if (t < NBLK) counts[t] = 0;
        float m = -3.0e38f;
        for (int i = t; i < NB * 4; i += 256) m = fmaxf(m, boxes[i]);
        for (int o = 32; o > 0; o >>= 1) m = fmaxf(m, __shfl_down(m, o));
        if ((t & 63) == 0) red[t >> 6] = m;
        __syncthreads();
        if (t == 0) *maxc = fmaxf(fmaxf(red[0], red[1]), fmaxf(red[2], red[3]));
    }
    __threadfence();
    grid.sync();

    // ================= Phase B: sparse edge extraction =================
    // 2080 triangular tiles over 1024 wave-slots, 3 uniform rounds
    float mc1 = maxc[0] + 1.0f;
    for (int round = 0; round < 3; ++round) {
        int tile = round * (GRID * 4) + blk * 4 + wave;
        bool active = tile < NTRI;
        int r = 0, cc = 0;
        float4 rb; float ra = 0.f;
        if (active) {
            int idx = tile;
            while (idx >= NBLK - r) { idx -= NBLK - r; ++r; }
            cc = r + idx;
            int jr = sidx[r * 64 + lane];
            float offr = (float)cls[jr] * mc1;
            rb = ((const float4*)boxes)[jr];
            rb.x += offr; rb.y += offr; rb.z += offr; rb.w += offr;
            ra = (rb.z - rb.x) * (rb.w - rb.y);
            if (cc == r) {
                cbs[wave][lane] = rb; cas[wave][lane] = ra;
            } else {
                int jc = sidx[cc * 64 + lane];
                float offc = (float)cls[jc] * mc1;
                float4 b = ((const float4*)boxes)[jc];
                b.x += offc; b.y += offc; b.z += offc; b.w += offc;
                cbs[wave][lane] = b;
                cas[wave][lane] = (b.z - b.x) * (b.w - b.y);
            }
        }
        __syncthreads();   // fence: per-wave LDS write -> cross-lane read
        if (active) {
            u64 w = 0;
#pragma unroll 8
            for (int j = 0; j < 64; ++j) {
                float4 b = cbs[wave][j];
                float xi = fminf(rb.z, b.z) - fmaxf(rb.x, b.x);
                float yi = fminf(rb.w, b.w) - fmaxf(rb.y, b.y);
                float inter = fmaxf(xi, 0.f) * fmaxf(yi, 0.f);
                float iou = inter / (ra + cas[wave][j] - inter);
                w |= (u64)(iou > IOU_THR) << j;
            }
            if (cc == r) w &= ~(1ull << lane);   // drop self-overlap bit
            if (w) {
                int slot = atomicAdd(&counts[r], 1);
                if (slot < ECAP)
                    entries[r * ECAP + slot] =
                        make_uint4((unsigned)(lane | (cc << 8)), 0u,
                                   (unsigned)(w & 0xffffffffull), (unsigned)(w >> 32));
            }
        }
        __syncthreads();
    }
    __threadfence();
    grid.sync();

    // ================= Phase C: serial greedy scan (block 0, wave 0) =========
    if (blk == 0 && wave == 0) {
        int cnt_l = counts[lane];       // lane b holds block b's entry count
        u64 accv = 0;                   // lane w = removed-word w
        u64 keptall = 0;                // lane b = keptm of block b
        u64 self = 1ull << lane;

        uint4 cur = entries[lane];      // depth-2 prefetch
        uint4 n1  = entries[ECAP + lane];
        for (int b = 0; b < NBLK; ++b) {
            uint4 n2;
            if (b < NBLK - 2) n2 = entries[(u64)(b + 2) * ECAP + lane];

            int cnt = __builtin_amdgcn_readlane(cnt_l, b);
            if (cnt > ECAP) cnt = ECAP;
            int cfast = cnt < 64 ? cnt : 64;

            // pass 1: build within-block column words from diagonal entries
            u64 colw = self;
            for (int e = 0; e < cfast; ++e) {
                unsigned meta = (unsigned)__builtin_amdgcn_readlane((int)cur.x, e);
                int l = meta & 255, c = meta >> 8;
                if (c == b) {
                    unsigned lo = (unsigned)__builtin_amdgcn_readlane((int)cur.z, e);
                    unsigned hi = (unsigned)__builtin_amdgcn_readlane((int)cur.w, e);
                    if (lane == l) colw |= ((u64)hi << 32) | lo;
                }
            }
            for (int e = 64; e < cnt; ++e) {        // overflow path (rare)
                uint4 x = entries[(u64)b * ECAP + e];
                int l = x.x & 255, c = x.x >> 8;
                if (c == b && lane == l) colw |= ((u64)x.w << 32) | x.z;
            }

            // decision: optimistic ballot; serial greedy only over conflicts
            u64 rem = readlane64(accv, b);
            u64 avail = ~rem;
            u64 edges = colw & avail & ~self;
            u64 involved = __ballot(edges != 0ull) & avail;
            u64 keptm = avail & ~involved;
            u64 sub = involved;
            while (sub) {
                int i = (int)__builtin_ctzll(sub);  // highest score first
                keptm |= 1ull << i;
                u64 ci = readlane64(colw, i);
                sub &= ~(ci | (1ull << i));
            }
            if (lane == b) keptall = keptm;

            // pass 2: merge kept rows' words into the removed accumulator
            for (int e = 0; e < cfast; ++e) {
                unsigned meta = (unsigned)__builtin_amdgcn_readlane((int)cur.x, e);
                unsigned lo   = (unsigned)__builtin_amdgcn_readlane((int)cur.z, e);
                unsigned hi   = (unsigned)__builtin_amdgcn_readlane((int)cur.w, e);
                int l = meta & 255, c = meta >> 8;
                if (((keptm >> l) & 1ull) && lane == c) accv |= ((u64)hi << 32) | lo;
            }
            for (int e = 64; e < cnt; ++e) {        // overflow path (rare)
                uint4 x = entries[(u64)b * ECAP + e];
                int l = x.x & 255, c = x.x >> 8;
                if (((keptm >> l) & 1ull) && lane == c) accv |= ((u64)x.w << 32) | x.z;
            }
            cur = n1; n1 = n2;
        }

        // epilogue: write keep mask via sorted-index scatter
#pragma unroll 8
        for (int bb = 0; bb < NBLK; ++bb) {
            u64 kw = readlane64(keptall, bb);
            int idx = sidx[bb * 64 + lane];
            keep_out[idx] = ((kw >> lane) & 1ull) ? 1.0f : 0.0f;
        }
    }
}

extern "C" void kernel_launch(void* const* d_in, const int* in_sizes, int n_in,
                              void* d_out, int out_size, void* d_ws, size_t ws_size,
                              hipStream_t stream) {
    const float* boxes   = (const float*)d_in[0];   // (4096,4)
    const float* scores  = (const float*)d_in[1];   // (4096,)
    const int*   cls     = (const int*)d_in[2];     // (4096,)
    const float* loc     = (const float*)d_in[3];   // (16384,2)
    const float* deltas  = (const float*)d_in[4];   // (16384,4)
    const int*   stride  = (const int*)d_in[5];     // scalar

    float* out = (float*)d_out;
    float* keep_out = out;          // 4096 floats (bool as 0/1)
    float* pred_out = out + NB;     // 16384*5 floats

    // workspace layout (16B-aligned pieces), ~1.05 MiB total
    char* ws = (char*)d_ws;
    float* maxc    = (float*)ws;                     ws += 16;
    int*   sidx    = (int*)ws;                       ws += NB * sizeof(int);
    int*   counts  = (int*)ws;                       ws += NBLK * sizeof(int) + 16;
    uint4* entries = (uint4*)ws;                     // NBLK * ECAP * 16 B = 1 MiB

    void* args[] = { (void*)&boxes, (void*)&scores, (void*)&cls, (void*)&loc,
                     (void*)&deltas, (void*)&stride, (void*)&keep_out,
                     (void*)&pred_out, (void*)&maxc, (void*)&sidx,
                     (void*)&counts, (void*)&entries };
    hipLaunchCooperativeKernel((const void*)fcos_fused, dim3(GRID), dim3(256),
                               args, 0, stream);
}

// Round 8
// 139.741 us; speedup vs baseline: 1.6644x; 1.6644x over previous
//
#include <hip/hip_runtime.h>
#include <stdint.h>

#define NB 4096          // number of boxes
#define NBLK 64          // 64 blocks of 64 boxes
#define IOU_THR 0.5f
#define ECAP 1024        // entry capacity per source block bucket
#define RANKB 256        // rank blocks (16 boxes each)
#define NTRI (NBLK * (NBLK + 1) / 2)   // 2080 upper-triangle tiles

typedef unsigned long long u64;

__device__ __forceinline__ u64 readlane64(u64 v, int lane) {
    unsigned lo = (unsigned)__builtin_amdgcn_readlane((int)(unsigned)(v & 0xffffffffull), lane);
    unsigned hi = (unsigned)__builtin_amdgcn_readlane((int)(unsigned)(v >> 32), lane);
    return ((u64)hi << 32) | (u64)lo;
}

// ------- fused front: pred (0-63), rank (64-319, wave-per-box), maxc (320) ---
__global__ void __launch_bounds__(256) fused_front(
        const float* __restrict__ boxes, const float* __restrict__ scores,
        const float* __restrict__ loc, const float* __restrict__ deltas,
        const int* __restrict__ stride_p,
        float* __restrict__ pred_out, float* __restrict__ maxc,
        int* __restrict__ sidx, int* __restrict__ counts) {
    __shared__ __align__(16) float sh[NB];
    __shared__ float red[4];
    int blk = blockIdx.x;
    int t = threadIdx.x;

    if (blk < 64) {
        // ---- pred boxes + centerness ----
        int i = blk * 256 + t;
        float s = (float)stride_p[0];
        float2 p = ((const float2*)loc)[i];
        float4 d = ((const float4*)deltas)[i];
        float c0 = fmaxf(d.x, 0.f), c1 = fmaxf(d.y, 0.f);
        float c2 = fmaxf(d.z, 0.f), c3 = fmaxf(d.w, 0.f);
        float b0 = p.x - c0 * s;
        float b1 = p.y - c1 * s;
        float b2 = p.x + c2 * s;
        float b3 = p.y + c3 * s;
        float lr_min = fminf(d.x, d.z), tb_min = fminf(d.y, d.w);
        float lr_max = fmaxf(d.x, d.z), tb_max = fmaxf(d.y, d.w);
        float cent = sqrtf((lr_min * tb_min) / (lr_max * tb_max));
        if (d.x == -1.f && d.y == -1.f && d.z == -1.f && d.w == -1.f) cent = -1.f;
        float* o = pred_out + (size_t)i * 5;
        o[0] = b0; o[1] = b1; o[2] = b2; o[3] = b3; o[4] = cent;
    } else if (blk < 64 + RANKB) {
        // ---- rank: one wave per box, 4 boxes/wave, 64-iteration j-loop ----
        for (int i = t; i < NB; i += 256) sh[i] = scores[i];
        __syncthreads();
        int wave = t >> 6, lane = t & 63;
        int base = (blk - 64) * 16 + wave * 4;     // 4 consecutive boxes
        float my0 = sh[base + 0], my1 = sh[base + 1];
        float my2 = sh[base + 2], my3 = sh[base + 3];
        int c0 = 0, c1 = 0, c2 = 0, c3 = 0;
#pragma unroll 8
        for (int k = 0; k < 64; ++k) {
            int j = lane + k * 64;                 // 2-way LDS bank alias: free
            float sj = sh[j];
            c0 += (sj > my0) || (sj == my0 && j < base + 0);
            c1 += (sj > my1) || (sj == my1 && j < base + 1);
            c2 += (sj > my2) || (sj == my2 && j < base + 2);
            c3 += (sj > my3) || (sj == my3 && j < base + 3);
        }
        for (int o = 32; o > 0; o >>= 1) {
            c0 += __shfl_down(c0, o); c1 += __shfl_down(c1, o);
            c2 += __shfl_down(c2, o); c3 += __shfl_down(c3, o);
        }
        if (lane == 0) {
            sidx[c0] = base + 0; sidx[c1] = base + 1;
            sidx[c2] = base + 2; sidx[c3] = base + 3;
        }
    } else {
        // ---- max coordinate + zero bucket counters (+ done counter) ----
        if (t < NBLK + 1) counts[t] = 0;
        float m = -3.0e38f;
        for (int i = t; i < NB * 4; i += 256) m = fmaxf(m, boxes[i]);
        for (int o = 32; o > 0; o >>= 1) m = fmaxf(m, __shfl_down(m, o));
        if ((t & 63) == 0) red[t >> 6] = m;
        __syncthreads();
        if (t == 0) *maxc = fmaxf(fmaxf(red[0], red[1]), fmaxf(red[2], red[3]));
    }
}

// -------- edge extraction (triangular, inline gather) + last-block scan ------
// Entry: .x = local_row | (word_col<<8), .z/.w = 64-bit word (lo/hi).
// The last block to finish its tile (device-scope atomic on done) runs the
// 1-wave greedy scan in place — removes a dispatch without any grid barrier.
__global__ void __launch_bounds__(64) edge_kernel(
        const float* __restrict__ boxes, const int* __restrict__ cls,
        const float* __restrict__ maxc, const int* __restrict__ sidx,
        int* __restrict__ counts, uint4* __restrict__ entries,
        float* __restrict__ keep_out) {
    // decode upper-triangle tile (r <= c) from linear block id (uniform scalar)
    int idx = blockIdx.x, r = 0;
    while (idx >= NBLK - r) { idx -= NBLK - r; ++r; }
    int c = r + idx;

    __shared__ float4 cb[64];
    __shared__ float ca[64];
    __shared__ int islast;
    int t = threadIdx.x;                // 64 threads = one wave
    float mc1 = maxc[0] + 1.0f;

    // gather row-tile box (sorted order) for this lane
    int jr = sidx[r * 64 + t];
    float offr = (float)cls[jr] * mc1;
    float4 rb = ((const float4*)boxes)[jr];
    rb.x += offr; rb.y += offr; rb.z += offr; rb.w += offr;
    float ra = (rb.z - rb.x) * (rb.w - rb.y);

    // column tile into LDS (reuse row tile when on the diagonal)
    if (c == r) {
        cb[t] = rb; ca[t] = ra;
    } else {
        int jc = sidx[c * 64 + t];
        float offc = (float)cls[jc] * mc1;
        float4 b = ((const float4*)boxes)[jc];
        b.x += offc; b.y += offc; b.z += offc; b.w += offc;
        cb[t] = b; ca[t] = (b.z - b.x) * (b.w - b.y);
    }
    __syncthreads();

    u64 w = 0;
#pragma unroll 8
    for (int j = 0; j < 64; ++j) {
        float4 b = cb[j];
        float xi = fminf(rb.z, b.z) - fmaxf(rb.x, b.x);
        float yi = fminf(rb.w, b.w) - fmaxf(rb.y, b.y);
        float inter = fmaxf(xi, 0.f) * fmaxf(yi, 0.f);
        float iou = inter / (ra + ca[j] - inter);
        w |= (u64)(iou > IOU_THR) << j;
    }
    if (c == r) w &= ~(1ull << t);      // drop self-overlap bit
    if (w) {
        int slot = atomicAdd(&counts[r], 1);
        if (slot < ECAP)
            entries[r * ECAP + slot] =
                make_uint4((unsigned)(t | (c << 8)), 0u,
                           (unsigned)(w & 0xffffffffull), (unsigned)(w >> 32));
    }

    // ---- last-finished-block detection (deadlock-free, device scope) ----
    __threadfence();                    // release: entry stores visible
    if (t == 0) {
        int old = atomicAdd(&counts[NBLK], 1);   // done counter
        islast = (old == NTRI - 1);
    }
    __syncthreads();
    if (!islast) return;
    __threadfence();                    // acquire: see all blocks' stores

    // ================= serial greedy scan (this one wave) =================
    const int lane = t;
    int cnt_l = counts[lane];           // lane b holds block b's entry count
    u64 accv = 0;                       // lane w = removed-word w
    u64 keptall = 0;                    // lane b = keptm of block b
    u64 self = 1ull << lane;

    uint4 cur = entries[lane];          // depth-2 prefetch
    uint4 n1  = entries[ECAP + lane];
    for (int b = 0; b < NBLK; ++b) {
        uint4 n2;
        if (b < NBLK - 2) n2 = entries[(u64)(b + 2) * ECAP + lane];

        int cnt = __builtin_amdgcn_readlane(cnt_l, b);
        if (cnt > ECAP) cnt = ECAP;
        int cfast = cnt < 64 ? cnt : 64;

        // pass 1: build within-block column words from diagonal entries
        u64 colw = self;
        for (int e = 0; e < cfast; ++e) {
            unsigned meta = (unsigned)__builtin_amdgcn_readlane((int)cur.x, e);
            int l = meta & 255, cw = meta >> 8;
            if (cw == b) {
                unsigned lo = (unsigned)__builtin_amdgcn_readlane((int)cur.z, e);
                unsigned hi = (unsigned)__builtin_amdgcn_readlane((int)cur.w, e);
                if (lane == l) colw |= ((u64)hi << 32) | lo;
            }
        }
        for (int e = 64; e < cnt; ++e) {        // overflow path (rare)
            uint4 x = entries[(u64)b * ECAP + e];
            int l = x.x & 255, cw = x.x >> 8;
            if (cw == b && lane == l) colw |= ((u64)x.w << 32) | x.z;
        }

        // decision: optimistic ballot; serial greedy only over conflicts
        u64 rem = readlane64(accv, b);
        u64 avail = ~rem;
        u64 edges = colw & avail & ~self;
        u64 involved = __ballot(edges != 0ull) & avail;
        u64 keptm = avail & ~involved;
        u64 sub = involved;
        while (sub) {
            int i = (int)__builtin_ctzll(sub);  // highest score first
            keptm |= 1ull << i;
            u64 ci = readlane64(colw, i);
            sub &= ~(ci | (1ull << i));
        }
        if (lane == b) keptall = keptm;

        // pass 2: merge kept rows' words into the removed accumulator
        for (int e = 0; e < cfast; ++e) {
            unsigned meta = (unsigned)__builtin_amdgcn_readlane((int)cur.x, e);
            unsigned lo   = (unsigned)__builtin_amdgcn_readlane((int)cur.z, e);
            unsigned hi   = (unsigned)__builtin_amdgcn_readlane((int)cur.w, e);
            int l = meta & 255, cw = meta >> 8;
            if (((keptm >> l) & 1ull) && lane == cw) accv |= ((u64)hi << 32) | lo;
        }
        for (int e = 64; e < cnt; ++e) {        // overflow path (rare)
            uint4 x = entries[(u64)b * ECAP + e];
            int l = x.x & 255, cw = x.x >> 8;
            if (((keptm >> l) & 1ull) && lane == cw) accv |= ((u64)x.w << 32) | x.z;
        }
        cur = n1; n1 = n2;
    }

    // epilogue: write keep mask via sorted-index scatter
#pragma unroll 8
    for (int bb = 0; bb < NBLK; ++bb) {
        u64 kw = readlane64(keptall, bb);
        int oidx = sidx[bb * 64 + lane];
        keep_out[oidx] = ((kw >> lane) & 1ull) ? 1.0f : 0.0f;
    }
}

extern "C" void kernel_launch(void* const* d_in, const int* in_sizes, int n_in,
                              void* d_out, int out_size, void* d_ws, size_t ws_size,
                              hipStream_t stream) {
    const float* boxes   = (const float*)d_in[0];   // (4096,4)
    const float* scores  = (const float*)d_in[1];   // (4096,)
    const int*   cls     = (const int*)d_in[2];     // (4096,)
    const float* loc     = (const float*)d_in[3];   // (16384,2)
    const float* deltas  = (const float*)d_in[4];   // (16384,4)
    const int*   stride  = (const int*)d_in[5];     // scalar

    float* out = (float*)d_out;
    float* keep_out = out;          // 4096 floats (bool as 0/1)
    float* pred_out = out + NB;     // 16384*5 floats

    // workspace layout (16B-aligned pieces), ~1.05 MiB total
    char* ws = (char*)d_ws;
    float* maxc    = (float*)ws;                     ws += 16;
    int*   sidx    = (int*)ws;                       ws += NB * sizeof(int);
    int*   counts  = (int*)ws;                       ws += (NBLK + 1) * sizeof(int) + 12;
    uint4* entries = (uint4*)ws;                     // NBLK * ECAP * 16 B = 1 MiB

    fused_front<<<64 + RANKB + 1, 256, 0, stream>>>(boxes, scores, loc, deltas, stride,
                                                    pred_out, maxc, sidx, counts);
    edge_kernel<<<NTRI, 64, 0, stream>>>(boxes, cls, maxc, sidx, counts, entries,
                                         keep_out);
}

// Round 9
// 125.441 us; speedup vs baseline: 1.8541x; 1.1140x over previous
//
#include <hip/hip_runtime.h>
#include <stdint.h>

#define NB 4096          // number of boxes
#define NBLK 64          // 64 blocks of 64 boxes
#define IOU_THR 0.5f
#define ECAP 1024        // entry capacity per source block bucket
#define RANKB 256        // rank blocks (16 boxes each)
#define NTRI (NBLK * (NBLK + 1) / 2)   // 2080 upper-triangle tiles

typedef unsigned long long u64;

__device__ __forceinline__ u64 readlane64(u64 v, int lane) {
    unsigned lo = (unsigned)__builtin_amdgcn_readlane((int)(unsigned)(v & 0xffffffffull), lane);
    unsigned hi = (unsigned)__builtin_amdgcn_readlane((int)(unsigned)(v >> 32), lane);
    return ((u64)hi << 32) | (u64)lo;
}

// ------- fused front: pred (0-63), rank (64-319, wave-per-box), maxc (320) ---
__global__ void __launch_bounds__(256) fused_front(
        const float* __restrict__ boxes, const float* __restrict__ scores,
        const float* __restrict__ loc, const float* __restrict__ deltas,
        const int* __restrict__ stride_p,
        float* __restrict__ pred_out, float* __restrict__ maxc,
        int* __restrict__ sidx, int* __restrict__ counts) {
    __shared__ __align__(16) float sh[NB];
    __shared__ float red[4];
    int blk = blockIdx.x;
    int t = threadIdx.x;

    if (blk < 64) {
        // ---- pred boxes + centerness ----
        int i = blk * 256 + t;
        float s = (float)stride_p[0];
        float2 p = ((const float2*)loc)[i];
        float4 d = ((const float4*)deltas)[i];
        float c0 = fmaxf(d.x, 0.f), c1 = fmaxf(d.y, 0.f);
        float c2 = fmaxf(d.z, 0.f), c3 = fmaxf(d.w, 0.f);
        float b0 = p.x - c0 * s;
        float b1 = p.y - c1 * s;
        float b2 = p.x + c2 * s;
        float b3 = p.y + c3 * s;
        float lr_min = fminf(d.x, d.z), tb_min = fminf(d.y, d.w);
        float lr_max = fmaxf(d.x, d.z), tb_max = fmaxf(d.y, d.w);
        float cent = sqrtf((lr_min * tb_min) / (lr_max * tb_max));
        if (d.x == -1.f && d.y == -1.f && d.z == -1.f && d.w == -1.f) cent = -1.f;
        float* o = pred_out + (size_t)i * 5;
        o[0] = b0; o[1] = b1; o[2] = b2; o[3] = b3; o[4] = cent;
    } else if (blk < 64 + RANKB) {
        // ---- rank: one wave per box, 4 boxes/wave, 64-iteration j-loop ----
        for (int i = t; i < NB; i += 256) sh[i] = scores[i];
        __syncthreads();
        int wave = t >> 6, lane = t & 63;
        int base = (blk - 64) * 16 + wave * 4;     // 4 consecutive boxes
        float my0 = sh[base + 0], my1 = sh[base + 1];
        float my2 = sh[base + 2], my3 = sh[base + 3];
        int c0 = 0, c1 = 0, c2 = 0, c3 = 0;
#pragma unroll 8
        for (int k = 0; k < 64; ++k) {
            int j = lane + k * 64;                 // 2-way LDS bank alias: free
            float sj = sh[j];
            c0 += (sj > my0) || (sj == my0 && j < base + 0);
            c1 += (sj > my1) || (sj == my1 && j < base + 1);
            c2 += (sj > my2) || (sj == my2 && j < base + 2);
            c3 += (sj > my3) || (sj == my3 && j < base + 3);
        }
        for (int o = 32; o > 0; o >>= 1) {
            c0 += __shfl_down(c0, o); c1 += __shfl_down(c1, o);
            c2 += __shfl_down(c2, o); c3 += __shfl_down(c3, o);
        }
        if (lane == 0) {
            sidx[c0] = base + 0; sidx[c1] = base + 1;
            sidx[c2] = base + 2; sidx[c3] = base + 3;
        }
    } else {
        // ---- max coordinate + zero bucket counters (+ done counter) ----
        if (t < NBLK + 1) counts[t] = 0;
        float m = -3.0e38f;
        for (int i = t; i < NB * 4; i += 256) m = fmaxf(m, boxes[i]);
        for (int o = 32; o > 0; o >>= 1) m = fmaxf(m, __shfl_down(m, o));
        if ((t & 63) == 0) red[t >> 6] = m;
        __syncthreads();
        if (t == 0) *maxc = fmaxf(fmaxf(red[0], red[1]), fmaxf(red[2], red[3]));
    }
}

// -------- edge extraction (triangular, inline gather) + last-block scan ------
// Entry (16 B): qword0 = local_row | (word_col<<8)  (high 32 = 0)
//               qword1 = 64-bit suppression word
// Entries are written with DEVICE-SCOPE 64-bit atomics (coherent point, no L2
// writeback needed) so blocks don't pay a release __threadfence each (round-8
// lesson: 2080 release fences cost ~45 us). A single s_waitcnt vmcnt(0)
// orders each block's entry atomics before its done-signal; only the last
// block pays one acquire __threadfence before scanning.
__global__ void __launch_bounds__(64) edge_kernel(
        const float* __restrict__ boxes, const int* __restrict__ cls,
        const float* __restrict__ maxc, const int* __restrict__ sidx,
        int* __restrict__ counts, uint4* __restrict__ entries,
        float* __restrict__ keep_out) {
    // decode upper-triangle tile (r <= c) from linear block id (uniform scalar)
    int idx = blockIdx.x, r = 0;
    while (idx >= NBLK - r) { idx -= NBLK - r; ++r; }
    int c = r + idx;

    __shared__ float4 cb[64];
    __shared__ float ca[64];
    __shared__ int islast;
    int t = threadIdx.x;                // 64 threads = one wave
    float mc1 = maxc[0] + 1.0f;

    // gather row-tile box (sorted order) for this lane
    int jr = sidx[r * 64 + t];
    float offr = (float)cls[jr] * mc1;
    float4 rb = ((const float4*)boxes)[jr];
    rb.x += offr; rb.y += offr; rb.z += offr; rb.w += offr;
    float ra = (rb.z - rb.x) * (rb.w - rb.y);

    // column tile into LDS (reuse row tile when on the diagonal)
    if (c == r) {
        cb[t] = rb; ca[t] = ra;
    } else {
        int jc = sidx[c * 64 + t];
        float offc = (float)cls[jc] * mc1;
        float4 b = ((const float4*)boxes)[jc];
        b.x += offc; b.y += offc; b.z += offc; b.w += offc;
        cb[t] = b; ca[t] = (b.z - b.x) * (b.w - b.y);
    }
    __syncthreads();

    u64 w = 0;
#pragma unroll 8
    for (int j = 0; j < 64; ++j) {
        float4 b = cb[j];
        float xi = fminf(rb.z, b.z) - fmaxf(rb.x, b.x);
        float yi = fminf(rb.w, b.w) - fmaxf(rb.y, b.y);
        float inter = fmaxf(xi, 0.f) * fmaxf(yi, 0.f);
        float iou = inter / (ra + ca[j] - inter);
        w |= (u64)(iou > IOU_THR) << j;
    }
    if (c == r) w &= ~(1ull << t);      // drop self-overlap bit
    if (w) {
        int slot = atomicAdd(&counts[r], 1);
        if (slot < ECAP) {
            u64* e = (u64*)&entries[r * ECAP + slot];
            atomicExch(e,     (u64)(unsigned)(t | (c << 8)));  // meta qword
            atomicExch(e + 1, w);                              // word qword
        }
    }

    // ---- last-finished-block detection (no per-block release fence) ----
    // wait own atomics' completion at the coherent point, then signal done
    asm volatile("s_waitcnt vmcnt(0)" ::: "memory");
    if (t == 0) {
        int old = atomicAdd(&counts[NBLK], 1);   // done counter (coherent)
        islast = (old == NTRI - 1);
    }
    __syncthreads();
    if (!islast) return;
    __threadfence();                    // acquire: invalidate stale L1/L2 once

    // ================= serial greedy scan (this one wave) =================
    const int lane = t;
    int cnt_l = counts[lane];           // lane b holds block b's entry count
    u64 accv = 0;                       // lane w = removed-word w
    u64 keptall = 0;                    // lane b = keptm of block b
    u64 self = 1ull << lane;

    uint4 cur = entries[lane];          // depth-2 prefetch
    uint4 n1  = entries[ECAP + lane];
    for (int b = 0; b < NBLK; ++b) {
        uint4 n2;
        if (b < NBLK - 2) n2 = entries[(u64)(b + 2) * ECAP + lane];

        int cnt = __builtin_amdgcn_readlane(cnt_l, b);
        if (cnt > ECAP) cnt = ECAP;
        int cfast = cnt < 64 ? cnt : 64;

        // pass 1: build within-block column words from diagonal entries
        u64 colw = self;
        for (int e = 0; e < cfast; ++e) {
            unsigned meta = (unsigned)__builtin_amdgcn_readlane((int)cur.x, e);
            int l = meta & 255, cw = meta >> 8;
            if (cw == b) {
                unsigned lo = (unsigned)__builtin_amdgcn_readlane((int)cur.z, e);
                unsigned hi = (unsigned)__builtin_amdgcn_readlane((int)cur.w, e);
                if (lane == l) colw |= ((u64)hi << 32) | lo;
            }
        }
        for (int e = 64; e < cnt; ++e) {        // overflow path (rare)
            uint4 x = entries[(u64)b * ECAP + e];
            int l = x.x & 255, cw = x.x >> 8;
            if (cw == b && lane == l) colw |= ((u64)x.w << 32) | x.z;
        }

        // decision: optimistic ballot; serial greedy only over conflicts
        u64 rem = readlane64(accv, b);
        u64 avail = ~rem;
        u64 edges = colw & avail & ~self;
        u64 involved = __ballot(edges != 0ull) & avail;
        u64 keptm = avail & ~involved;
        u64 sub = involved;
        while (sub) {
            int i = (int)__builtin_ctzll(sub);  // highest score first
            keptm |= 1ull << i;
            u64 ci = readlane64(colw, i);
            sub &= ~(ci | (1ull << i));
        }
        if (lane == b) keptall = keptm;

        // pass 2: merge kept rows' words into the removed accumulator
        for (int e = 0; e < cfast; ++e) {
            unsigned meta = (unsigned)__builtin_amdgcn_readlane((int)cur.x, e);
            unsigned lo   = (unsigned)__builtin_amdgcn_readlane((int)cur.z, e);
            unsigned hi   = (unsigned)__builtin_amdgcn_readlane((int)cur.w, e);
            int l = meta & 255, cw = meta >> 8;
            if (((keptm >> l) & 1ull) && lane == cw) accv |= ((u64)hi << 32) | lo;
        }
        for (int e = 64; e < cnt; ++e) {        // overflow path (rare)
            uint4 x = entries[(u64)b * ECAP + e];
            int l = x.x & 255, cw = x.x >> 8;
            if (((keptm >> l) & 1ull) && lane == cw) accv |= ((u64)x.w << 32) | x.z;
        }
        cur = n1; n1 = n2;
    }

    // epilogue: write keep mask via sorted-index scatter
#pragma unroll 8
    for (int bb = 0; bb < NBLK; ++bb) {
        u64 kw = readlane64(keptall, bb);
        int oidx = sidx[bb * 64 + lane];
        keep_out[oidx] = ((kw >> lane) & 1ull) ? 1.0f : 0.0f;
    }
}

extern "C" void kernel_launch(void* const* d_in, const int* in_sizes, int n_in,
                              void* d_out, int out_size, void* d_ws, size_t ws_size,
                              hipStream_t stream) {
    const float* boxes   = (const float*)d_in[0];   // (4096,4)
    const float* scores  = (const float*)d_in[1];   // (4096,)
    const int*   cls     = (const int*)d_in[2];     // (4096,)
    const float* loc     = (const float*)d_in[3];   // (16384,2)
    const float* deltas  = (const float*)d_in[4];   // (16384,4)
    const int*   stride  = (const int*)d_in[5];     // scalar

    float* out = (float*)d_out;
    float* keep_out = out;          // 4096 floats (bool as 0/1)
    float* pred_out = out + NB;     // 16384*5 floats

    // workspace layout (16B-aligned pieces), ~1.05 MiB total
    char* ws = (char*)d_ws;
    float* maxc    = (float*)ws;                     ws += 16;
    int*   sidx    = (int*)ws;                       ws += NB * sizeof(int);
    int*   counts  = (int*)ws;                       ws += (NBLK + 1) * sizeof(int) + 12;
    uint4* entries = (uint4*)ws;                     // NBLK * ECAP * 16 B = 1 MiB

    fused_front<<<64 + RANKB + 1, 256, 0, stream>>>(boxes, scores, loc, deltas, stride,
                                                    pred_out, maxc, sidx, counts);
    edge_kernel<<<NTRI, 64, 0, stream>>>(boxes, cls, maxc, sidx, counts, entries,
                                         keep_out);
}